// Round 3
// baseline (343.754 us; speedup 1.0000x reference)
//
#include <hip/hip_runtime.h>

typedef __attribute__((ext_vector_type(8))) short short8;
typedef __attribute__((ext_vector_type(16))) float f32x16;

#define Bsz 256
#define Cch 3
#define Him 224
#define Wim 224
#define RET 32
#define HG 1024
#define HL 256
#define GDIM 9216
#define NOUT 1280

__device__ __forceinline__ unsigned short f2bf(float x) {
  unsigned u = __float_as_uint(x);
  return (unsigned short)((u + 0x7fffu + ((u >> 16) & 1u)) >> 16);
}
__device__ __forceinline__ float bf2f(unsigned short h) {
  return __uint_as_float((unsigned)h << 16);
}

// ---------------------------------------------------------------------------
// Foveate -> bf16 hi/lo planes g[256][9216] (k-contiguous rows = MFMA-A ready)
// ---------------------------------------------------------------------------
__global__ __launch_bounds__(256) void foveate_kernel(
    const float* __restrict__ img, const float* __restrict__ loc,
    unsigned short* __restrict__ ghi, unsigned short* __restrict__ glo) {
  int idx = blockIdx.x * 256 + threadIdx.x;
  int b = idx / GDIM;
  int r = idx - b * GDIM;
  int z = r / (Cch * RET * RET);
  int r2 = r - z * (Cch * RET * RET);
  int c = r2 / (RET * RET);
  int p = r2 - c * (RET * RET);
  int i = p >> 5, j = p & 31;
  float dr = (loc[b * 2 + 0] + 1.f) * .5f * (float)Wim;
  float dc = (loc[b * 2 + 1] + 1.f) * .5f * (float)Wim;
  int half = 16 << z;
  int top = (int)truncf(dr - (float)half), left = (int)truncf(dc - (float)half);
  const float* base = img + ((long)b * Cch + c) * (Him * Wim);
  float v;
  if (z == 0) {
    v = base[(top + i) * Wim + left + j];
  } else {
    int rr = (z == 1) ? top + 2 * i : top + 4 * i + 1;
    int cc = (z == 1) ? left + 2 * j : left + 4 * j + 1;
    v = .25f * (base[rr * Wim + cc] + base[rr * Wim + cc + 1] +
                base[(rr + 1) * Wim + cc] + base[(rr + 1) * Wim + cc + 1]);
  }
  unsigned short h = f2bf(v);
  ghi[idx] = h;
  glo[idx] = f2bf(v - bf2f(h));
}

// ---------------------------------------------------------------------------
// GEMM core: block 128(M)x128(N), BK=32, 4 waves as 2x2 of 64x64 wave tiles,
// v_mfma_f32_32x32x16_bf16, bf16x3 (AhBh + AhBl + AlBh) fp32-split emulation.
// A: precomputed bf16 hi/lo planes [M][K]; staged frag-linear (conflict-free).
// B: fp32 [K][N] read directly; staged [k][n] in LDS; each lane gathers its
//    fragment with 8 ds_read_b32 (conflict-free) and converts to hi/lo.
// ---------------------------------------------------------------------------
__device__ __forceinline__ void gemm_block(
    const unsigned short* __restrict__ Ahi, const unsigned short* __restrict__ Alo,
    int lda, const float* __restrict__ Bf, int ldb,
    int m0, int n0, int kb, int iters,
    f32x16 acc[2][2], unsigned short* __restrict__ ldsA, float* __restrict__ ldsB) {
  const int t = threadIdx.x;
  const int lane = t & 63;
  const int wm = t >> 7, wn = (t >> 6) & 1;
  const int l5 = lane & 31, lh = lane >> 5;

  // staging source/dest (slot s = plane*512 + mf*128 + kseg*32 + m5; 8 shorts/slot)
  const unsigned short* aSrc[4];
  const float* bSrc[4];
  int aDst[4], bDst[4];
#pragma unroll
  for (int p = 0; p < 4; ++p) {
    int s = p * 256 + t;
    int m5 = s & 31, kseg = (s >> 5) & 3, mf = (s >> 7) & 3;
    const unsigned short* base = (s >> 9) ? Alo : Ahi;
    aSrc[p] = base + (long)(m0 + mf * 32 + m5) * lda + kb + kseg * 8;
    aDst[p] = s * 8;
    bSrc[p] = Bf + (long)(kb + (s & 1023) / 32) * ldb + n0 + (s & 31) * 4;
    bDst[p] = ((s & 1023) >> 5) * 128 + (s & 31) * 4;
  }

  for (int it = 0; it < iters; ++it) {
    uint4 av[4];
    float4 bv[4];
#pragma unroll
    for (int p = 0; p < 4; ++p) {
      av[p] = *(const uint4*)(aSrc[p] + it * 32);
      bv[p] = *(const float4*)(bSrc[p] + (long)it * 32 * ldb);
    }
    __syncthreads();
#pragma unroll
    for (int p = 0; p < 4; ++p) {
      *(uint4*)(ldsA + aDst[p]) = av[p];
      *(float4*)(ldsB + bDst[p]) = bv[p];
    }
    __syncthreads();
#pragma unroll
    for (int ks = 0; ks < 2; ++ks) {
      short8 ah[2], al[2], bh[2], bl[2];
#pragma unroll
      for (int mi = 0; mi < 2; ++mi) {
        int mf = wm * 2 + mi;
        int slot = mf * 128 + (ks * 2 + lh) * 32 + l5;
        ah[mi] = *(const short8*)(ldsA + slot * 8);
        al[mi] = *(const short8*)(ldsA + (slot + 512) * 8);
      }
#pragma unroll
      for (int ni = 0; ni < 2; ++ni) {
        int n = wn * 64 + ni * 32 + l5;
        int k0 = ks * 16 + lh * 8;
        short8 hh, ll;
#pragma unroll
        for (int j = 0; j < 8; ++j) {
          float v = ldsB[(k0 + j) * 128 + n];
          unsigned short h = f2bf(v);
          hh[j] = (short)h;
          ll[j] = (short)f2bf(v - bf2f(h));
        }
        bh[ni] = hh;
        bl[ni] = ll;
      }
#pragma unroll
      for (int mi = 0; mi < 2; ++mi)
#pragma unroll
        for (int ni = 0; ni < 2; ++ni) {
          acc[mi][ni] = __builtin_amdgcn_mfma_f32_32x32x16_bf16(ah[mi], bh[ni], acc[mi][ni], 0, 0, 0);
          acc[mi][ni] = __builtin_amdgcn_mfma_f32_32x32x16_bf16(ah[mi], bl[ni], acc[mi][ni], 0, 0, 0);
          acc[mi][ni] = __builtin_amdgcn_mfma_f32_32x32x16_bf16(al[mi], bh[ni], acc[mi][ni], 0, 0, 0);
        }
    }
  }
}

// C/D layout (32x32): col = lane&31, row = (reg&3) + 8*(reg>>2) + 4*(lane>>5)
__device__ __forceinline__ void epilogue(float* __restrict__ Pz, int ldp, int m0,
                                         int n0, f32x16 acc[2][2]) {
  const int t = threadIdx.x, lane = t & 63;
  const int wm = t >> 7, wn = (t >> 6) & 1;
  const int l5 = lane & 31, lh = lane >> 5;
#pragma unroll
  for (int mi = 0; mi < 2; ++mi)
#pragma unroll
    for (int ni = 0; ni < 2; ++ni) {
      int col = n0 + wn * 64 + ni * 32 + l5;
      int rbase = m0 + wm * 64 + mi * 32 + 4 * lh;
#pragma unroll
      for (int r = 0; r < 16; ++r) {
        int row = rbase + (r & 3) + 8 * (r >> 2);
        Pz[(long)row * ldp + col] = acc[mi][ni][r];
      }
    }
}

// gemm1: P1[z][256][1024] = g @ W1 chunk; splitK=32 (chunk 288 = 9 iters BK32)
__global__ __launch_bounds__(256, 2) void gemm1_kernel(
    const unsigned short* __restrict__ ghi, const unsigned short* __restrict__ glo,
    const float* __restrict__ W1, float* __restrict__ P) {
  __shared__ __align__(16) unsigned short ldsA[8192];
  __shared__ __align__(16) float ldsB[4096];
  f32x16 zz = {0, 0, 0, 0, 0, 0, 0, 0, 0, 0, 0, 0, 0, 0, 0, 0};
  f32x16 acc[2][2] = {zz, zz, zz, zz};
  int n0 = blockIdx.x * 128, m0 = blockIdx.y * 128, z = blockIdx.z;
  gemm_block(ghi, glo, GDIM, W1, HG, m0, n0, z * 288, 9, acc, ldsA, ldsB);
  epilogue(P + (long)z * Bsz * HG, HG, m0, n0, acc);
}

// gemm2: z<8 -> h1@W3 K-chunk z*128; z=8,9 -> h2@W4 K-chunk (z-8)*128
__global__ __launch_bounds__(256, 2) void gemm2_kernel(
    const unsigned short* __restrict__ h1hi, const unsigned short* __restrict__ h1lo,
    const unsigned short* __restrict__ h2hi, const unsigned short* __restrict__ h2lo,
    const float* __restrict__ W3, const float* __restrict__ W4,
    float* __restrict__ P) {
  __shared__ __align__(16) unsigned short ldsA[8192];
  __shared__ __align__(16) float ldsB[4096];
  f32x16 zz = {0, 0, 0, 0, 0, 0, 0, 0, 0, 0, 0, 0, 0, 0, 0, 0};
  f32x16 acc[2][2] = {zz, zz, zz, zz};
  int n0 = blockIdx.x * 128, m0 = blockIdx.y * 128, z = blockIdx.z;
  if (z < 8)
    gemm_block(h1hi, h1lo, HG, W3, NOUT, m0, n0, z * 128, 4, acc, ldsA, ldsB);
  else
    gemm_block(h2hi, h2lo, HL, W4, NOUT, m0, n0, (z - 8) * 128, 4, acc, ldsA, ldsB);
  epilogue(P + (long)z * Bsz * NOUT, NOUT, m0, n0, acc);
}

// reduce1 (blocks 0..255): h1 = relu(b1 + sum_{z<32} P1[z]) -> bf16 hi/lo
// h2 part (blocks 256..319): h2 = relu(loc @ W2 + b2)       -> bf16 hi/lo
__global__ __launch_bounds__(256) void reduce1_h2_kernel(
    const float* __restrict__ P, const float* __restrict__ b1,
    const float* __restrict__ loc, const float* __restrict__ W2,
    const float* __restrict__ b2,
    unsigned short* __restrict__ h1hi, unsigned short* __restrict__ h1lo,
    unsigned short* __restrict__ h2hi, unsigned short* __restrict__ h2lo) {
  if (blockIdx.x < 256) {
    int i4 = (blockIdx.x * 256 + threadIdx.x) * 4;
    float4 s = *(const float4*)(P + i4);
    for (int z = 1; z < 32; ++z) {
      float4 p = *(const float4*)(P + (long)z * (Bsz * HG) + i4);
      s.x += p.x; s.y += p.y; s.z += p.z; s.w += p.w;
    }
    int n = i4 & (HG - 1);
    float4 bb = *(const float4*)(b1 + n);
    float v0 = fmaxf(s.x + bb.x, 0.f), v1 = fmaxf(s.y + bb.y, 0.f);
    float v2 = fmaxf(s.z + bb.z, 0.f), v3 = fmaxf(s.w + bb.w, 0.f);
    unsigned short h0 = f2bf(v0), h1 = f2bf(v1), h2 = f2bf(v2), h3 = f2bf(v3);
    *(ushort4*)(h1hi + i4) = make_ushort4(h0, h1, h2, h3);
    *(ushort4*)(h1lo + i4) = make_ushort4(f2bf(v0 - bf2f(h0)), f2bf(v1 - bf2f(h1)),
                                          f2bf(v2 - bf2f(h2)), f2bf(v3 - bf2f(h3)));
  } else {
    int i4 = ((blockIdx.x - 256) * 256 + threadIdx.x) * 4;
    int b = i4 >> 8, n = i4 & (HL - 1);
    float l0 = loc[b * 2 + 0], l1 = loc[b * 2 + 1];
    float4 w0 = *(const float4*)(W2 + n);
    float4 w1 = *(const float4*)(W2 + HL + n);
    float4 bb = *(const float4*)(b2 + n);
    float v0 = fmaxf(fmaf(l0, w0.x, fmaf(l1, w1.x, bb.x)), 0.f);
    float v1 = fmaxf(fmaf(l0, w0.y, fmaf(l1, w1.y, bb.y)), 0.f);
    float v2 = fmaxf(fmaf(l0, w0.z, fmaf(l1, w1.z, bb.z)), 0.f);
    float v3 = fmaxf(fmaf(l0, w0.w, fmaf(l1, w1.w, bb.w)), 0.f);
    unsigned short h0 = f2bf(v0), h1 = f2bf(v1), h2 = f2bf(v2), h3 = f2bf(v3);
    *(ushort4*)(h2hi + i4) = make_ushort4(h0, h1, h2, h3);
    *(ushort4*)(h2lo + i4) = make_ushort4(f2bf(v0 - bf2f(h0)), f2bf(v1 - bf2f(h1)),
                                          f2bf(v2 - bf2f(h2)), f2bf(v3 - bf2f(h3)));
  }
}

// reduce2: out = relu(relu(b3 + sum_{z<8} P2[z]) + relu(b4 + P2[8] + P2[9]))
__global__ __launch_bounds__(256) void reduce2_kernel(
    const float* __restrict__ P, const float* __restrict__ b3,
    const float* __restrict__ b4, float* __restrict__ out) {
  int i4 = (blockIdx.x * 256 + threadIdx.x) * 4;
  float4 a = *(const float4*)(P + i4);
  for (int z = 1; z < 8; ++z) {
    float4 p = *(const float4*)(P + (long)z * (Bsz * NOUT) + i4);
    a.x += p.x; a.y += p.y; a.z += p.z; a.w += p.w;
  }
  float4 c8 = *(const float4*)(P + 8L * (Bsz * NOUT) + i4);
  float4 c9 = *(const float4*)(P + 9L * (Bsz * NOUT) + i4);
  int n = i4 % NOUT;
  float4 b3v = *(const float4*)(b3 + n);
  float4 b4v = *(const float4*)(b4 + n);
  float4 o;
  o.x = fmaxf(fmaxf(a.x + b3v.x, 0.f) + fmaxf(c8.x + c9.x + b4v.x, 0.f), 0.f);
  o.y = fmaxf(fmaxf(a.y + b3v.y, 0.f) + fmaxf(c8.y + c9.y + b4v.y, 0.f), 0.f);
  o.z = fmaxf(fmaxf(a.z + b3v.z, 0.f) + fmaxf(c8.z + c9.z + b4v.z, 0.f), 0.f);
  o.w = fmaxf(fmaxf(a.w + b3v.w, 0.f) + fmaxf(c8.w + c9.w + b4v.w, 0.f), 0.f);
  *(float4*)(out + i4) = o;
}

extern "C" void kernel_launch(void* const* d_in, const int* in_sizes, int n_in,
                              void* d_out, int out_size, void* d_ws, size_t ws_size,
                              hipStream_t stream) {
  const float* images = (const float*)d_in[0];
  const float* locs = (const float*)d_in[1];
  const float* W1 = (const float*)d_in[2];
  const float* b1 = (const float*)d_in[3];
  const float* W2 = (const float*)d_in[4];
  const float* b2 = (const float*)d_in[5];
  const float* W3 = (const float*)d_in[6];
  const float* b3 = (const float*)d_in[7];
  const float* W4 = (const float*)d_in[8];
  const float* b4 = (const float*)d_in[9];
  float* out = (float*)d_out;

  unsigned short* ghi = (unsigned short*)d_ws;
  unsigned short* glo = ghi + (long)Bsz * GDIM;
  unsigned short* h1hi = glo + (long)Bsz * GDIM;
  unsigned short* h1lo = h1hi + (long)Bsz * HG;
  unsigned short* h2hi = h1lo + (long)Bsz * HG;
  unsigned short* h2lo = h2hi + (long)Bsz * HL;
  float* P1 = (float*)(h2lo + (long)Bsz * HL);   // 32*256*1024 fp32
  float* P2 = P1 + 32L * Bsz * HG;               // 10*256*1280 fp32

  foveate_kernel<<<(Bsz * GDIM) / 256, 256, 0, stream>>>(images, locs, ghi, glo);
  gemm1_kernel<<<dim3(HG / 128, Bsz / 128, 32), 256, 0, stream>>>(ghi, glo, W1, P1);
  reduce1_h2_kernel<<<320, 256, 0, stream>>>(P1, b1, locs, W2, b2, h1hi, h1lo, h2hi, h2lo);
  gemm2_kernel<<<dim3(NOUT / 128, Bsz / 128, 10), 256, 0, stream>>>(
      h1hi, h1lo, h2hi, h2lo, W3, W4, P2);
  reduce2_kernel<<<(Bsz * NOUT) / 1024, 256, 0, stream>>>(P2, b3, b4, out);
}

// Round 4
// 330.414 us; speedup vs baseline: 1.0404x; 1.0404x over previous
//
#include <hip/hip_runtime.h>

typedef __attribute__((ext_vector_type(8))) short short8;
typedef __attribute__((ext_vector_type(16))) float f32x16;

#define Bsz 256
#define Cch 3
#define Him 224
#define Wim 224
#define RET 32
#define HG 1024
#define HL 256
#define GDIM 9216
#define NOUT 1280

__device__ __forceinline__ unsigned short f2bf(float x) {
  unsigned u = __float_as_uint(x);
  return (unsigned short)((u + 0x7fffu + ((u >> 16) & 1u)) >> 16);
}
__device__ __forceinline__ float bf2f(unsigned short h) {
  return __uint_as_float((unsigned)h << 16);
}

// ---------------------------------------------------------------------------
// Foveate -> blocked bf16 hi/lo: gs[k>>3][b(256)][k&7], k = flat glimpse idx
// ---------------------------------------------------------------------------
__global__ __launch_bounds__(256) void foveate_kernel(
    const float* __restrict__ img, const float* __restrict__ loc,
    unsigned short* __restrict__ ghi, unsigned short* __restrict__ glo) {
  int idx = blockIdx.x * 256 + threadIdx.x;
  int b = idx / GDIM;
  int r = idx - b * GDIM;  // k
  int z = r / (Cch * RET * RET);
  int r2 = r - z * (Cch * RET * RET);
  int c = r2 / (RET * RET);
  int p = r2 - c * (RET * RET);
  int i = p >> 5, j = p & 31;
  float dr = (loc[b * 2 + 0] + 1.f) * .5f * (float)Wim;
  float dc = (loc[b * 2 + 1] + 1.f) * .5f * (float)Wim;
  int half = 16 << z;
  int top = (int)truncf(dr - (float)half), left = (int)truncf(dc - (float)half);
  const float* base = img + ((long)b * Cch + c) * (Him * Wim);
  float v;
  if (z == 0) {
    v = base[(top + i) * Wim + left + j];
  } else {
    int rr = (z == 1) ? top + 2 * i : top + 4 * i + 1;
    int cc = (z == 1) ? left + 2 * j : left + 4 * j + 1;
    v = .25f * (base[rr * Wim + cc] + base[rr * Wim + cc + 1] +
                base[(rr + 1) * Wim + cc] + base[(rr + 1) * Wim + cc + 1]);
  }
  unsigned short h = f2bf(v);
  int off = (r >> 3) * 2048 + b * 8 + (r & 7);
  ghi[off] = h;
  glo[off] = f2bf(v - bf2f(h));
}

// ---------------------------------------------------------------------------
// Transpose+split: in[K][N] fp32 -> blocked hi/lo out[k>>3][N][k&7] bf16.
// 16 B contiguous stores (full slot per thread).
// ---------------------------------------------------------------------------
__global__ __launch_bounds__(256) void tconv_kernel(
    const float* __restrict__ in, unsigned short* __restrict__ oh,
    unsigned short* __restrict__ ol, int K, int N) {
  __shared__ float tile[32][33];
  int n0 = blockIdx.x * 32, k0 = blockIdx.y * 32;
  int r = threadIdx.x >> 3, c4 = (threadIdx.x & 7) * 4;
  float4 v = *(const float4*)(in + (long)(k0 + r) * N + n0 + c4);
  tile[r][c4 + 0] = v.x; tile[r][c4 + 1] = v.y;
  tile[r][c4 + 2] = v.z; tile[r][c4 + 3] = v.w;
  __syncthreads();
  if (threadIdx.x < 128) {
    int rr = threadIdx.x >> 2, c8 = (threadIdx.x & 3) * 8;
    unsigned hi01 = 0, hi23 = 0, hi45 = 0, hi67 = 0;
    unsigned lo01 = 0, lo23 = 0, lo45 = 0, lo67 = 0;
    unsigned hh[8], ll[8];
#pragma unroll
    for (int j = 0; j < 8; ++j) {
      float x = tile[c8 + j][rr];
      hh[j] = f2bf(x);
      ll[j] = f2bf(x - bf2f((unsigned short)hh[j]));
    }
    hi01 = hh[0] | (hh[1] << 16); hi23 = hh[2] | (hh[3] << 16);
    hi45 = hh[4] | (hh[5] << 16); hi67 = hh[6] | (hh[7] << 16);
    lo01 = ll[0] | (ll[1] << 16); lo23 = ll[2] | (ll[3] << 16);
    lo45 = ll[4] | (ll[5] << 16); lo67 = ll[6] | (ll[7] << 16);
    long off = (long)((k0 + c8) >> 3) * (N * 8) + (n0 + rr) * 8;
    *(uint4*)(oh + off) = make_uint4(hi01, hi23, hi45, hi67);
    *(uint4*)(ol + off) = make_uint4(lo01, lo23, lo45, lo67);
  }
}

// ---------------------------------------------------------------------------
// GEMM core: BM=256 (full M), BN=128, BK=32, 256 threads = 4 waves, each wave
// a 64(M)x128(N) tile of 2x4 32x32x16 MFMA frags; bf16x3 fp32-split.
// A blocked [kblk][256][8], B blocked [kblk][Bn][8]; LDS mirrors the layout so
// staging = contiguous uint4 copies, frag reads = contiguous ds_read_b128.
// Register-prefetch: loads for it+1 in flight during compute(it).
// ---------------------------------------------------------------------------
__device__ __forceinline__ void gemm_core(
    const unsigned short* __restrict__ Ahi, const unsigned short* __restrict__ Alo,
    const unsigned short* __restrict__ Bhi, const unsigned short* __restrict__ Blo,
    int Bn, int n0, int kblk0, int iters, f32x16 acc[2][4],
    unsigned short* __restrict__ lds) {
  const int t = threadIdx.x, w = t >> 6, lane = t & 63;
  const int l5 = lane & 31, lh = lane >> 5;
  unsigned short* lAh = lds;
  unsigned short* lAl = lds + 8192;
  unsigned short* lBh = lds + 16384;
  unsigned short* lBl = lds + 20480;

  uint4 rAh[4], rAl[4], rBh[2], rBl[2];
  long aoff[4], boff[2];
#pragma unroll
  for (int q = 0; q < 4; ++q) aoff[q] = (long)kblk0 * 2048 + (q * 256 + t) * 8;
#pragma unroll
  for (int q = 0; q < 2; ++q) {
    int s = q * 256 + t;
    boff[q] = ((long)kblk0 + (s >> 7)) * Bn * 8 + (long)(n0 + (s & 127)) * 8;
  }
#pragma unroll
  for (int q = 0; q < 4; ++q) {
    rAh[q] = *(const uint4*)(Ahi + aoff[q]);
    rAl[q] = *(const uint4*)(Alo + aoff[q]);
  }
#pragma unroll
  for (int q = 0; q < 2; ++q) {
    rBh[q] = *(const uint4*)(Bhi + boff[q]);
    rBl[q] = *(const uint4*)(Blo + boff[q]);
  }

  for (int it = 0; it < iters; ++it) {
    __syncthreads();
#pragma unroll
    for (int q = 0; q < 4; ++q) {
      *(uint4*)(lAh + (q * 256 + t) * 8) = rAh[q];
      *(uint4*)(lAl + (q * 256 + t) * 8) = rAl[q];
    }
#pragma unroll
    for (int q = 0; q < 2; ++q) {
      *(uint4*)(lBh + (q * 256 + t) * 8) = rBh[q];
      *(uint4*)(lBl + (q * 256 + t) * 8) = rBl[q];
    }
    __syncthreads();
    if (it + 1 < iters) {
      long ka = (long)(it + 1) * 8192;           // 4 kblks * 2048 shorts
      long kb = (long)(it + 1) * 4 * Bn * 8;
#pragma unroll
      for (int q = 0; q < 4; ++q) {
        rAh[q] = *(const uint4*)(Ahi + aoff[q] + ka);
        rAl[q] = *(const uint4*)(Alo + aoff[q] + ka);
      }
#pragma unroll
      for (int q = 0; q < 2; ++q) {
        rBh[q] = *(const uint4*)(Bhi + boff[q] + kb);
        rBl[q] = *(const uint4*)(Blo + boff[q] + kb);
      }
    }
#pragma unroll
    for (int ks = 0; ks < 2; ++ks) {
      short8 fa[2][2], fb[2][4];
#pragma unroll
      for (int mi = 0; mi < 2; ++mi) {
        int off = ((ks * 2 + lh) * 256 + w * 64 + mi * 32 + l5) * 8;
        fa[0][mi] = *(const short8*)(lAh + off);
        fa[1][mi] = *(const short8*)(lAl + off);
      }
#pragma unroll
      for (int ni = 0; ni < 4; ++ni) {
        int off = ((ks * 2 + lh) * 128 + ni * 32 + l5) * 8;
        fb[0][ni] = *(const short8*)(lBh + off);
        fb[1][ni] = *(const short8*)(lBl + off);
      }
      // term-major: 8 independent MFMAs between reuses of the same acc
#pragma unroll
      for (int mi = 0; mi < 2; ++mi)
#pragma unroll
        for (int ni = 0; ni < 4; ++ni)
          acc[mi][ni] = __builtin_amdgcn_mfma_f32_32x32x16_bf16(fa[0][mi], fb[0][ni], acc[mi][ni], 0, 0, 0);
#pragma unroll
      for (int mi = 0; mi < 2; ++mi)
#pragma unroll
        for (int ni = 0; ni < 4; ++ni)
          acc[mi][ni] = __builtin_amdgcn_mfma_f32_32x32x16_bf16(fa[0][mi], fb[1][ni], acc[mi][ni], 0, 0, 0);
#pragma unroll
      for (int mi = 0; mi < 2; ++mi)
#pragma unroll
        for (int ni = 0; ni < 4; ++ni)
          acc[mi][ni] = __builtin_amdgcn_mfma_f32_32x32x16_bf16(fa[1][mi], fb[0][ni], acc[mi][ni], 0, 0, 0);
    }
  }
}

// C/D 32x32: col = lane&31, row = (reg&3) + 8*(reg>>2) + 4*(lane>>5)
__device__ __forceinline__ void epilogue(float* __restrict__ Pz, int ldp, int n0,
                                         f32x16 acc[2][4]) {
  const int t = threadIdx.x, w = t >> 6, lane = t & 63;
  const int l5 = lane & 31, lh = lane >> 5;
#pragma unroll
  for (int mi = 0; mi < 2; ++mi)
#pragma unroll
    for (int ni = 0; ni < 4; ++ni) {
      int col = n0 + ni * 32 + l5;
      int rbase = w * 64 + mi * 32 + 4 * lh;
#pragma unroll
      for (int r = 0; r < 16; ++r) {
        int row = rbase + (r & 3) + 8 * (r >> 2);
        Pz[(long)row * ldp + col] = acc[mi][ni][r];
      }
    }
}

// gemm1: P1[z][256][1024], z<32, K-chunk 288 (kblk0 = z*36, 9 iters)
__global__ __launch_bounds__(256, 1) void gemm1_kernel(
    const unsigned short* __restrict__ ghi, const unsigned short* __restrict__ glo,
    const unsigned short* __restrict__ w1hi, const unsigned short* __restrict__ w1lo,
    float* __restrict__ P) {
  __shared__ __align__(16) unsigned short lds[24576];
  f32x16 acc[2][4];
#pragma unroll
  for (int i = 0; i < 2; ++i)
#pragma unroll
    for (int j = 0; j < 4; ++j)
#pragma unroll
      for (int r = 0; r < 16; ++r) acc[i][j][r] = 0.f;
  int n0 = blockIdx.x * 128, z = blockIdx.y;
  gemm_core(ghi, glo, w1hi, w1lo, HG, n0, z * 36, 9, acc, lds);
  epilogue(P + (long)z * Bsz * HG, HG, n0, acc);
}

// gemm2: z<8 -> h1@W3 chunk (kblk z*16); z=8,9 -> h2@W4 chunk ((z-8)*16)
__global__ __launch_bounds__(256, 1) void gemm2_kernel(
    const unsigned short* __restrict__ h1hi, const unsigned short* __restrict__ h1lo,
    const unsigned short* __restrict__ h2hi, const unsigned short* __restrict__ h2lo,
    const unsigned short* __restrict__ w3hi, const unsigned short* __restrict__ w3lo,
    const unsigned short* __restrict__ w4hi, const unsigned short* __restrict__ w4lo,
    float* __restrict__ P) {
  __shared__ __align__(16) unsigned short lds[24576];
  f32x16 acc[2][4];
#pragma unroll
  for (int i = 0; i < 2; ++i)
#pragma unroll
    for (int j = 0; j < 4; ++j)
#pragma unroll
      for (int r = 0; r < 16; ++r) acc[i][j][r] = 0.f;
  int n0 = blockIdx.x * 128, z = blockIdx.y;
  if (z < 8)
    gemm_core(h1hi, h1lo, w3hi, w3lo, NOUT, n0, z * 16, 4, acc, lds);
  else
    gemm_core(h2hi, h2lo, w4hi, w4lo, NOUT, n0, (z - 8) * 16, 4, acc, lds);
  epilogue(P + (long)z * Bsz * NOUT, NOUT, n0, acc);
}

// reduce1 (bx<256): h1 = relu(b1 + sum_{z<32} P1[z]) -> blocked hi/lo
// h2 (bx>=256): h2 = relu(loc @ W2 + b2)             -> blocked hi/lo
__global__ __launch_bounds__(256) void reduce1_h2_kernel(
    const float* __restrict__ P, const float* __restrict__ b1,
    const float* __restrict__ loc, const float* __restrict__ W2,
    const float* __restrict__ b2,
    unsigned short* __restrict__ h1hi, unsigned short* __restrict__ h1lo,
    unsigned short* __restrict__ h2hi, unsigned short* __restrict__ h2lo) {
  if (blockIdx.x < 256) {
    int i4 = (blockIdx.x * 256 + threadIdx.x) * 4;
    float4 s = *(const float4*)(P + i4);
    for (int z = 1; z < 32; ++z) {
      float4 p = *(const float4*)(P + (long)z * (Bsz * HG) + i4);
      s.x += p.x; s.y += p.y; s.z += p.z; s.w += p.w;
    }
    int m = i4 >> 10, k = i4 & (HG - 1);
    float4 bb = *(const float4*)(b1 + k);
    float v0 = fmaxf(s.x + bb.x, 0.f), v1 = fmaxf(s.y + bb.y, 0.f);
    float v2 = fmaxf(s.z + bb.z, 0.f), v3 = fmaxf(s.w + bb.w, 0.f);
    unsigned short h0 = f2bf(v0), h1 = f2bf(v1), h2 = f2bf(v2), h3 = f2bf(v3);
    int off = (k >> 3) * 2048 + m * 8 + (k & 7);
    *(ushort4*)(h1hi + off) = make_ushort4(h0, h1, h2, h3);
    *(ushort4*)(h1lo + off) = make_ushort4(f2bf(v0 - bf2f(h0)), f2bf(v1 - bf2f(h1)),
                                           f2bf(v2 - bf2f(h2)), f2bf(v3 - bf2f(h3)));
  } else {
    int i4 = ((blockIdx.x - 256) * 256 + threadIdx.x) * 4;
    int b = i4 >> 8, k = i4 & (HL - 1);
    float l0 = loc[b * 2 + 0], l1 = loc[b * 2 + 1];
    float4 w0 = *(const float4*)(W2 + k);
    float4 w1 = *(const float4*)(W2 + HL + k);
    float4 bb = *(const float4*)(b2 + k);
    float v0 = fmaxf(fmaf(l0, w0.x, fmaf(l1, w1.x, bb.x)), 0.f);
    float v1 = fmaxf(fmaf(l0, w0.y, fmaf(l1, w1.y, bb.y)), 0.f);
    float v2 = fmaxf(fmaf(l0, w0.z, fmaf(l1, w1.z, bb.z)), 0.f);
    float v3 = fmaxf(fmaf(l0, w0.w, fmaf(l1, w1.w, bb.w)), 0.f);
    unsigned short h0 = f2bf(v0), h1 = f2bf(v1), h2 = f2bf(v2), h3 = f2bf(v3);
    int off = (k >> 3) * 2048 + b * 8 + (k & 7);
    *(ushort4*)(h2hi + off) = make_ushort4(h0, h1, h2, h3);
    *(ushort4*)(h2lo + off) = make_ushort4(f2bf(v0 - bf2f(h0)), f2bf(v1 - bf2f(h1)),
                                           f2bf(v2 - bf2f(h2)), f2bf(v3 - bf2f(h3)));
  }
}

// reduce2: out = relu(relu(b3 + sum_{z<8} P2[z]) + relu(b4 + P2[8] + P2[9]))
__global__ __launch_bounds__(256) void reduce2_kernel(
    const float* __restrict__ P, const float* __restrict__ b3,
    const float* __restrict__ b4, float* __restrict__ out) {
  int i4 = (blockIdx.x * 256 + threadIdx.x) * 4;
  float4 a = *(const float4*)(P + i4);
  for (int z = 1; z < 8; ++z) {
    float4 p = *(const float4*)(P + (long)z * (Bsz * NOUT) + i4);
    a.x += p.x; a.y += p.y; a.z += p.z; a.w += p.w;
  }
  float4 c8 = *(const float4*)(P + 8L * (Bsz * NOUT) + i4);
  float4 c9 = *(const float4*)(P + 9L * (Bsz * NOUT) + i4);
  int n = i4 % NOUT;
  float4 b3v = *(const float4*)(b3 + n);
  float4 b4v = *(const float4*)(b4 + n);
  float4 o;
  o.x = fmaxf(fmaxf(a.x + b3v.x, 0.f) + fmaxf(c8.x + c9.x + b4v.x, 0.f), 0.f);
  o.y = fmaxf(fmaxf(a.y + b3v.y, 0.f) + fmaxf(c8.y + c9.y + b4v.y, 0.f), 0.f);
  o.z = fmaxf(fmaxf(a.z + b3v.z, 0.f) + fmaxf(c8.z + c9.z + b4v.z, 0.f), 0.f);
  o.w = fmaxf(fmaxf(a.w + b3v.w, 0.f) + fmaxf(c8.w + c9.w + b4v.w, 0.f), 0.f);
  *(float4*)(out + i4) = o;
}

extern "C" void kernel_launch(void* const* d_in, const int* in_sizes, int n_in,
                              void* d_out, int out_size, void* d_ws, size_t ws_size,
                              hipStream_t stream) {
  const float* images = (const float*)d_in[0];
  const float* locs = (const float*)d_in[1];
  const float* W1 = (const float*)d_in[2];
  const float* b1 = (const float*)d_in[3];
  const float* W2 = (const float*)d_in[4];
  const float* b2 = (const float*)d_in[5];
  const float* W3 = (const float*)d_in[6];
  const float* b3 = (const float*)d_in[7];
  const float* W4 = (const float*)d_in[8];
  const float* b4 = (const float*)d_in[9];
  float* out = (float*)d_out;

  unsigned short* p = (unsigned short*)d_ws;
  unsigned short* gsh = p; p += 2359296;
  unsigned short* gsl = p; p += 2359296;
  unsigned short* w1h = p; p += 9437184;
  unsigned short* w1l = p; p += 9437184;
  unsigned short* w3h = p; p += 1310720;
  unsigned short* w3l = p; p += 1310720;
  unsigned short* w4h = p; p += 327680;
  unsigned short* w4l = p; p += 327680;
  unsigned short* h1h = p; p += 262144;
  unsigned short* h1l = p; p += 262144;
  unsigned short* h2h = p; p += 65536;
  unsigned short* h2l = p; p += 65536;
  float* P1 = (float*)p;            // 32*256*1024 = 8,388,608 floats
  float* P2 = P1 + 8388608;         // 10*256*1280 = 3,276,800 floats

  tconv_kernel<<<dim3(HG / 32, GDIM / 32), 256, 0, stream>>>(W1, w1h, w1l, GDIM, HG);
  tconv_kernel<<<dim3(NOUT / 32, HG / 32), 256, 0, stream>>>(W3, w3h, w3l, HG, NOUT);
  tconv_kernel<<<dim3(NOUT / 32, HL / 32), 256, 0, stream>>>(W4, w4h, w4l, HL, NOUT);
  foveate_kernel<<<(Bsz * GDIM) / 256, 256, 0, stream>>>(images, locs, gsh, gsl);
  gemm1_kernel<<<dim3(8, 32), 256, 0, stream>>>(gsh, gsl, w1h, w1l, P1);
  reduce1_h2_kernel<<<320, 256, 0, stream>>>(P1, b1, locs, W2, b2, h1h, h1l, h2h, h2l);
  gemm2_kernel<<<dim3(10, 10), 256, 0, stream>>>(h1h, h1l, h2h, h2l, w3h, w3l, w4h, w4l, P2);
  reduce2_kernel<<<(Bsz * NOUT) / 1024, 256, 0, stream>>>(P2, b3, b4, out);
}

// Round 5
// 329.236 us; speedup vs baseline: 1.0441x; 1.0036x over previous
//
#include <hip/hip_runtime.h>

typedef __attribute__((ext_vector_type(8))) short short8;
typedef __attribute__((ext_vector_type(16))) float f32x16;

#define Bsz 256
#define Cch 3
#define Him 224
#define Wim 224
#define RET 32
#define HG 1024
#define HL 256
#define GDIM 9216
#define NOUT 1280

__device__ __forceinline__ unsigned short f2bf(float x) {
  unsigned u = __float_as_uint(x);
  return (unsigned short)((u + 0x7fffu + ((u >> 16) & 1u)) >> 16);
}
__device__ __forceinline__ float bf2f(unsigned short h) {
  return __uint_as_float((unsigned)h << 16);
}

// ---------------------------------------------------------------------------
// Foveate -> blocked bf16 hi/lo: g[k>>3][b(256)][k&7]
// ---------------------------------------------------------------------------
__global__ __launch_bounds__(256) void foveate_kernel(
    const float* __restrict__ img, const float* __restrict__ loc,
    unsigned short* __restrict__ ghi, unsigned short* __restrict__ glo) {
  int idx = blockIdx.x * 256 + threadIdx.x;
  int b = idx / GDIM;
  int r = idx - b * GDIM;
  int z = r / (Cch * RET * RET);
  int r2 = r - z * (Cch * RET * RET);
  int c = r2 / (RET * RET);
  int p = r2 - c * (RET * RET);
  int i = p >> 5, j = p & 31;
  float dr = (loc[b * 2 + 0] + 1.f) * .5f * (float)Wim;
  float dc = (loc[b * 2 + 1] + 1.f) * .5f * (float)Wim;
  int half = 16 << z;
  int top = (int)truncf(dr - (float)half), left = (int)truncf(dc - (float)half);
  const float* base = img + ((long)b * Cch + c) * (Him * Wim);
  float v;
  if (z == 0) {
    v = base[(top + i) * Wim + left + j];
  } else {
    int rr = (z == 1) ? top + 2 * i : top + 4 * i + 1;
    int cc = (z == 1) ? left + 2 * j : left + 4 * j + 1;
    v = .25f * (base[rr * Wim + cc] + base[rr * Wim + cc + 1] +
                base[(rr + 1) * Wim + cc] + base[(rr + 1) * Wim + cc + 1]);
  }
  unsigned short h = f2bf(v);
  int off = (r >> 3) * 2048 + b * 8 + (r & 7);
  ghi[off] = h;
  glo[off] = f2bf(v - bf2f(h));
}

// ---------------------------------------------------------------------------
// Fused transpose+split for W1/W3/W4: in[K][N] fp32 -> blocked [k>>3][N][k&7]
// ---------------------------------------------------------------------------
__global__ __launch_bounds__(256) void tconv_all_kernel(
    const float* __restrict__ W1, unsigned short* __restrict__ w1h, unsigned short* __restrict__ w1l,
    const float* __restrict__ W3, unsigned short* __restrict__ w3h, unsigned short* __restrict__ w3l,
    const float* __restrict__ W4, unsigned short* __restrict__ w4h, unsigned short* __restrict__ w4l) {
  __shared__ float tile[32][33];
  int bx = blockIdx.x;
  const float* in;
  unsigned short *oh, *ol;
  int K, N, lb;
  if (bx < 9216)       { in = W1; oh = w1h; ol = w1l; K = GDIM; N = HG;   lb = bx; }
  else if (bx < 10496) { in = W3; oh = w3h; ol = w3l; K = HG;   N = NOUT; lb = bx - 9216; }
  else                 { in = W4; oh = w4h; ol = w4l; K = HL;   N = NOUT; lb = bx - 10496; }
  int nb = N >> 5;
  int n0 = (lb % nb) * 32, k0 = (lb / nb) * 32;
  int r = threadIdx.x >> 3, c4 = (threadIdx.x & 7) * 4;
  float4 v = *(const float4*)(in + (long)(k0 + r) * N + n0 + c4);
  tile[r][c4 + 0] = v.x; tile[r][c4 + 1] = v.y;
  tile[r][c4 + 2] = v.z; tile[r][c4 + 3] = v.w;
  __syncthreads();
  if (threadIdx.x < 128) {
    int rr = threadIdx.x >> 2, c8 = (threadIdx.x & 3) * 8;
    unsigned hh[8], ll[8];
#pragma unroll
    for (int j = 0; j < 8; ++j) {
      float x = tile[c8 + j][rr];
      hh[j] = f2bf(x);
      ll[j] = f2bf(x - bf2f((unsigned short)hh[j]));
    }
    long off = (long)((k0 + c8) >> 3) * (N * 8) + (n0 + rr) * 8;
    *(uint4*)(oh + off) = make_uint4(hh[0] | (hh[1] << 16), hh[2] | (hh[3] << 16),
                                     hh[4] | (hh[5] << 16), hh[6] | (hh[7] << 16));
    *(uint4*)(ol + off) = make_uint4(ll[0] | (ll[1] << 16), ll[2] | (ll[3] << 16),
                                     ll[4] | (ll[5] << 16), ll[6] | (ll[7] << 16));
  }
}

// ---------------------------------------------------------------------------
// GEMM core: BM=128, BN=128, BK=32 (4 kblks of 8), 4 waves as 2x2 of 64x64,
// 32x32x16 MFMA, bf16x3. Blocked global layouts [kblk][rows][8]; LDS mirrors
// => contiguous uint4 staging + contiguous ds_read_b128 frags (0 conflicts).
// Register prefetch of iter+1 overlaps global latency with compute.
// ---------------------------------------------------------------------------
__device__ __forceinline__ void gemm_core(
    const unsigned short* __restrict__ Ahi, const unsigned short* __restrict__ Alo,
    int Mtot, int m0,
    const unsigned short* __restrict__ Bhi, const unsigned short* __restrict__ Blo,
    int Ntot, int n0,
    int kblk0, int iters, f32x16 acc[2][2], unsigned short* __restrict__ lds) {
  const int t = threadIdx.x, lane = t & 63;
  const int wm = t >> 7, wn = (t >> 6) & 1;
  const int l5 = lane & 31, lh = lane >> 5;
  unsigned short* lAh = lds;
  unsigned short* lAl = lds + 4096;
  unsigned short* lBh = lds + 8192;
  unsigned short* lBl = lds + 12288;

  long aoff[2], boff[2];
#pragma unroll
  for (int q = 0; q < 2; ++q) {
    int s = q * 256 + t;
    int kb = s >> 7, rr = s & 127;
    aoff[q] = ((long)(kblk0 + kb) * Mtot + m0 + rr) * 8;
    boff[q] = ((long)(kblk0 + kb) * Ntot + n0 + rr) * 8;
  }
  const long da4 = (long)4 * Mtot * 8, db4 = (long)4 * Ntot * 8;
  uint4 rAh[2], rAl[2], rBh[2], rBl[2];
#pragma unroll
  for (int q = 0; q < 2; ++q) {
    rAh[q] = *(const uint4*)(Ahi + aoff[q]);
    rAl[q] = *(const uint4*)(Alo + aoff[q]);
    rBh[q] = *(const uint4*)(Bhi + boff[q]);
    rBl[q] = *(const uint4*)(Blo + boff[q]);
  }

  for (int it = 0; it < iters; ++it) {
    __syncthreads();
#pragma unroll
    for (int q = 0; q < 2; ++q) {
      int d = (q * 256 + t) * 8;
      *(uint4*)(lAh + d) = rAh[q];
      *(uint4*)(lAl + d) = rAl[q];
      *(uint4*)(lBh + d) = rBh[q];
      *(uint4*)(lBl + d) = rBl[q];
    }
    __syncthreads();
    if (it + 1 < iters) {
#pragma unroll
      for (int q = 0; q < 2; ++q) {
        aoff[q] += da4; boff[q] += db4;
        rAh[q] = *(const uint4*)(Ahi + aoff[q]);
        rAl[q] = *(const uint4*)(Alo + aoff[q]);
        rBh[q] = *(const uint4*)(Bhi + boff[q]);
        rBl[q] = *(const uint4*)(Blo + boff[q]);
      }
    }
#pragma unroll
    for (int ks = 0; ks < 2; ++ks) {
      short8 fah[2], fal[2], fbh[2], fbl[2];
#pragma unroll
      for (int mi = 0; mi < 2; ++mi) {
        int off = ((ks * 2 + lh) * 128 + wm * 64 + mi * 32 + l5) * 8;
        fah[mi] = *(const short8*)(lAh + off);
        fal[mi] = *(const short8*)(lAl + off);
      }
#pragma unroll
      for (int ni = 0; ni < 2; ++ni) {
        int off = ((ks * 2 + lh) * 128 + wn * 64 + ni * 32 + l5) * 8;
        fbh[ni] = *(const short8*)(lBh + off);
        fbl[ni] = *(const short8*)(lBl + off);
      }
#pragma unroll
      for (int mi = 0; mi < 2; ++mi)
#pragma unroll
        for (int ni = 0; ni < 2; ++ni)
          acc[mi][ni] = __builtin_amdgcn_mfma_f32_32x32x16_bf16(fah[mi], fbh[ni], acc[mi][ni], 0, 0, 0);
#pragma unroll
      for (int mi = 0; mi < 2; ++mi)
#pragma unroll
        for (int ni = 0; ni < 2; ++ni)
          acc[mi][ni] = __builtin_amdgcn_mfma_f32_32x32x16_bf16(fah[mi], fbl[ni], acc[mi][ni], 0, 0, 0);
#pragma unroll
      for (int mi = 0; mi < 2; ++mi)
#pragma unroll
        for (int ni = 0; ni < 2; ++ni)
          acc[mi][ni] = __builtin_amdgcn_mfma_f32_32x32x16_bf16(fal[mi], fbh[ni], acc[mi][ni], 0, 0, 0);
    }
  }
}

// C/D 32x32: col = lane&31, row = (reg&3) + 8*(reg>>2) + 4*(lane>>5)
__device__ __forceinline__ void epilogue(float* __restrict__ Pz, int ldp, int m0,
                                         int n0, f32x16 acc[2][2]) {
  const int t = threadIdx.x, lane = t & 63;
  const int wm = t >> 7, wn = (t >> 6) & 1;
  const int l5 = lane & 31, lh = lane >> 5;
#pragma unroll
  for (int mi = 0; mi < 2; ++mi)
#pragma unroll
    for (int ni = 0; ni < 2; ++ni) {
      int col = n0 + wn * 64 + ni * 32 + l5;
      int rbase = m0 + wm * 64 + mi * 32 + 4 * lh;
#pragma unroll
      for (int r = 0; r < 16; ++r) {
        int row = rbase + (r & 3) + 8 * (r >> 2);
        Pz[(long)row * ldp + col] = acc[mi][ni][r];
      }
    }
}

// gemm1: grid (8 n, 2 m, 32 z); P1[z] += g[m-chunk] @ W1 (K-chunk 288 = 9 it)
__global__ __launch_bounds__(256, 2) void gemm1_kernel(
    const unsigned short* __restrict__ ghi, const unsigned short* __restrict__ glo,
    const unsigned short* __restrict__ w1h, const unsigned short* __restrict__ w1l,
    float* __restrict__ P) {
  __shared__ __align__(16) unsigned short lds[16384];
  f32x16 acc[2][2];
#pragma unroll
  for (int i = 0; i < 2; ++i)
#pragma unroll
    for (int j = 0; j < 2; ++j)
#pragma unroll
      for (int r = 0; r < 16; ++r) acc[i][j][r] = 0.f;
  int n0 = blockIdx.x * 128, m0 = blockIdx.y * 128, z = blockIdx.z;
  gemm_core(ghi, glo, Bsz, m0, w1h, w1l, HG, n0, z * 36, 9, acc, lds);
  epilogue(P + (long)z * Bsz * HG, HG, m0, n0, acc);
}

// gemm2: grid (10 n, 2 m, 20 z); z<16: h1@W3 chunk 64 (kblk z*8, 2 it);
//        z>=16: h2@W4 chunk 64 (kblk (z-16)*8, 2 it)
__global__ __launch_bounds__(256, 2) void gemm2_kernel(
    const unsigned short* __restrict__ h1h, const unsigned short* __restrict__ h1l,
    const unsigned short* __restrict__ h2h, const unsigned short* __restrict__ h2l,
    const unsigned short* __restrict__ w3h, const unsigned short* __restrict__ w3l,
    const unsigned short* __restrict__ w4h, const unsigned short* __restrict__ w4l,
    float* __restrict__ P) {
  __shared__ __align__(16) unsigned short lds[16384];
  f32x16 acc[2][2];
#pragma unroll
  for (int i = 0; i < 2; ++i)
#pragma unroll
    for (int j = 0; j < 2; ++j)
#pragma unroll
      for (int r = 0; r < 16; ++r) acc[i][j][r] = 0.f;
  int n0 = blockIdx.x * 128, m0 = blockIdx.y * 128, z = blockIdx.z;
  if (z < 16)
    gemm_core(h1h, h1l, Bsz, m0, w3h, w3l, NOUT, n0, z * 8, 2, acc, lds);
  else
    gemm_core(h2h, h2l, Bsz, m0, w4h, w4l, NOUT, n0, (z - 16) * 8, 2, acc, lds);
  epilogue(P + (long)z * Bsz * NOUT, NOUT, m0, n0, acc);
}

// reduce1 (bx<256): h1 = relu(b1 + sum_{z<32} P1[z]) -> blocked hi/lo
// h2 (bx>=256): h2 = relu(loc @ W2 + b2)             -> blocked hi/lo
__global__ __launch_bounds__(256) void reduce1_h2_kernel(
    const float* __restrict__ P, const float* __restrict__ b1,
    const float* __restrict__ loc, const float* __restrict__ W2,
    const float* __restrict__ b2,
    unsigned short* __restrict__ h1h, unsigned short* __restrict__ h1l,
    unsigned short* __restrict__ h2h, unsigned short* __restrict__ h2l) {
  if (blockIdx.x < 256) {
    int i4 = (blockIdx.x * 256 + threadIdx.x) * 4;
    float4 s = *(const float4*)(P + i4);
    for (int z = 1; z < 32; ++z) {
      float4 p = *(const float4*)(P + (long)z * (Bsz * HG) + i4);
      s.x += p.x; s.y += p.y; s.z += p.z; s.w += p.w;
    }
    int m = i4 >> 10, k = i4 & (HG - 1);
    float4 bb = *(const float4*)(b1 + k);
    float v0 = fmaxf(s.x + bb.x, 0.f), v1 = fmaxf(s.y + bb.y, 0.f);
    float v2 = fmaxf(s.z + bb.z, 0.f), v3 = fmaxf(s.w + bb.w, 0.f);
    unsigned short h0 = f2bf(v0), h1 = f2bf(v1), h2 = f2bf(v2), h3 = f2bf(v3);
    int off = (k >> 3) * 2048 + m * 8 + (k & 7);
    *(ushort4*)(h1h + off) = make_ushort4(h0, h1, h2, h3);
    *(ushort4*)(h1l + off) = make_ushort4(f2bf(v0 - bf2f(h0)), f2bf(v1 - bf2f(h1)),
                                          f2bf(v2 - bf2f(h2)), f2bf(v3 - bf2f(h3)));
  } else {
    int i4 = ((blockIdx.x - 256) * 256 + threadIdx.x) * 4;
    int b = i4 >> 8, k = i4 & (HL - 1);
    float l0 = loc[b * 2 + 0], l1 = loc[b * 2 + 1];
    float4 w0 = *(const float4*)(W2 + k);
    float4 w1 = *(const float4*)(W2 + HL + k);
    float4 bb = *(const float4*)(b2 + k);
    float v0 = fmaxf(fmaf(l0, w0.x, fmaf(l1, w1.x, bb.x)), 0.f);
    float v1 = fmaxf(fmaf(l0, w0.y, fmaf(l1, w1.y, bb.y)), 0.f);
    float v2 = fmaxf(fmaf(l0, w0.z, fmaf(l1, w1.z, bb.z)), 0.f);
    float v3 = fmaxf(fmaf(l0, w0.w, fmaf(l1, w1.w, bb.w)), 0.f);
    unsigned short h0 = f2bf(v0), h1 = f2bf(v1), h2 = f2bf(v2), h3 = f2bf(v3);
    int off = (k >> 3) * 2048 + b * 8 + (k & 7);
    *(ushort4*)(h2h + off) = make_ushort4(h0, h1, h2, h3);
    *(ushort4*)(h2l + off) = make_ushort4(f2bf(v0 - bf2f(h0)), f2bf(v1 - bf2f(h1)),
                                          f2bf(v2 - bf2f(h2)), f2bf(v3 - bf2f(h3)));
  }
}

// reduce2: out = relu(relu(b3 + sum_{z<16} P2[z]) + relu(b4 + sum_{z=16..19}))
__global__ __launch_bounds__(256) void reduce2_kernel(
    const float* __restrict__ P, const float* __restrict__ b3,
    const float* __restrict__ b4, float* __restrict__ out) {
  int i4 = (blockIdx.x * 256 + threadIdx.x) * 4;
  const long S = (long)Bsz * NOUT;
  float4 a = *(const float4*)(P + i4);
  for (int z = 1; z < 16; ++z) {
    float4 p = *(const float4*)(P + z * S + i4);
    a.x += p.x; a.y += p.y; a.z += p.z; a.w += p.w;
  }
  float4 c = *(const float4*)(P + 16 * S + i4);
  for (int z = 17; z < 20; ++z) {
    float4 p = *(const float4*)(P + z * S + i4);
    c.x += p.x; c.y += p.y; c.z += p.z; c.w += p.w;
  }
  int n = i4 % NOUT;
  float4 b3v = *(const float4*)(b3 + n);
  float4 b4v = *(const float4*)(b4 + n);
  float4 o;
  o.x = fmaxf(fmaxf(a.x + b3v.x, 0.f) + fmaxf(c.x + b4v.x, 0.f), 0.f);
  o.y = fmaxf(fmaxf(a.y + b3v.y, 0.f) + fmaxf(c.y + b4v.y, 0.f), 0.f);
  o.z = fmaxf(fmaxf(a.z + b3v.z, 0.f) + fmaxf(c.z + b4v.z, 0.f), 0.f);
  o.w = fmaxf(fmaxf(a.w + b3v.w, 0.f) + fmaxf(c.w + b4v.w, 0.f), 0.f);
  *(float4*)(out + i4) = o;
}

extern "C" void kernel_launch(void* const* d_in, const int* in_sizes, int n_in,
                              void* d_out, int out_size, void* d_ws, size_t ws_size,
                              hipStream_t stream) {
  const float* images = (const float*)d_in[0];
  const float* locs = (const float*)d_in[1];
  const float* W1 = (const float*)d_in[2];
  const float* b1 = (const float*)d_in[3];
  const float* W2 = (const float*)d_in[4];
  const float* b2 = (const float*)d_in[5];
  const float* W3 = (const float*)d_in[6];
  const float* b3 = (const float*)d_in[7];
  const float* W4 = (const float*)d_in[8];
  const float* b4 = (const float*)d_in[9];
  float* out = (float*)d_out;

  unsigned short* p = (unsigned short*)d_ws;
  unsigned short* gsh = p; p += 2359296;
  unsigned short* gsl = p; p += 2359296;
  unsigned short* w1h = p; p += 9437184;
  unsigned short* w1l = p; p += 9437184;
  unsigned short* w3h = p; p += 1310720;
  unsigned short* w3l = p; p += 1310720;
  unsigned short* w4h = p; p += 327680;
  unsigned short* w4l = p; p += 327680;
  unsigned short* h1h = p; p += 262144;
  unsigned short* h1l = p; p += 262144;
  unsigned short* h2h = p; p += 65536;
  unsigned short* h2l = p; p += 65536;
  float* P1 = (float*)p;            // 32*256*1024 = 8,388,608 floats
  float* P2 = P1 + 8388608;         // 20*256*1280 = 6,553,600 floats

  tconv_all_kernel<<<10816, 256, 0, stream>>>(W1, w1h, w1l, W3, w3h, w3l, W4, w4h, w4l);
  foveate_kernel<<<(Bsz * GDIM) / 256, 256, 0, stream>>>(images, locs, gsh, gsl);
  gemm1_kernel<<<dim3(8, 2, 32), 256, 0, stream>>>(gsh, gsl, w1h, w1l, P1);
  reduce1_h2_kernel<<<320, 256, 0, stream>>>(P1, b1, locs, W2, b2, h1h, h1l, h2h, h2l);
  gemm2_kernel<<<dim3(10, 2, 20), 256, 0, stream>>>(h1h, h1l, h2h, h2l, w3h, w3l, w4h, w4l, P2);
  reduce2_kernel<<<(Bsz * NOUT) / 1024, 256, 0, stream>>>(P2, b3, b4, out);
}

// Round 6
// 307.168 us; speedup vs baseline: 1.1191x; 1.0718x over previous
//
#include <hip/hip_runtime.h>

typedef __attribute__((ext_vector_type(8))) short short8;
typedef __attribute__((ext_vector_type(16))) float f32x16;

#define Bsz 256
#define Cch 3
#define Him 224
#define Wim 224
#define RET 32
#define HG 1024
#define HL 256
#define GDIM 9216
#define NOUT 1280

__device__ __forceinline__ unsigned short f2bf(float x) {
  unsigned u = __float_as_uint(x);
  return (unsigned short)((u + 0x7fffu + ((u >> 16) & 1u)) >> 16);
}
__device__ __forceinline__ float bf2f(unsigned short h) {
  return __uint_as_float((unsigned)h << 16);
}

// ---------------------------------------------------------------------------
// Foveate -> blocked bf16 hi/lo: g[k>>3][b(256)][k&7]; 4 outputs per thread.
// ---------------------------------------------------------------------------
__global__ __launch_bounds__(256) void foveate_kernel(
    const float* __restrict__ img, const float* __restrict__ loc,
    unsigned short* __restrict__ ghi, unsigned short* __restrict__ glo) {
  int idx4 = (blockIdx.x * 256 + threadIdx.x) * 4;
  int b = idx4 / GDIM;
  int r = idx4 - b * GDIM;                  // quad-aligned glimpse index
  int z = r / (Cch * RET * RET);
  int r2 = r - z * (Cch * RET * RET);
  int c = r2 / (RET * RET);
  int p = r2 - c * (RET * RET);
  int i = p >> 5, j = p & 31;               // j quad-aligned
  float dr = (loc[b * 2 + 0] + 1.f) * .5f * (float)Wim;
  float dc = (loc[b * 2 + 1] + 1.f) * .5f * (float)Wim;
  int half = 16 << z;
  int top = (int)truncf(dr - (float)half), left = (int)truncf(dc - (float)half);
  const float* base = img + ((long)b * Cch + c) * (Him * Wim);
  float v[4];
  if (z == 0) {
    const float* p0 = base + (top + i) * Wim + left + j;
#pragma unroll
    for (int q = 0; q < 4; ++q) v[q] = p0[q];
  } else if (z == 1) {
    const float* p0 = base + (top + 2 * i) * Wim + left + 2 * j;
    const float* p1 = p0 + Wim;
#pragma unroll
    for (int q = 0; q < 4; ++q)
      v[q] = .25f * (p0[2 * q] + p0[2 * q + 1] + p1[2 * q] + p1[2 * q + 1]);
  } else {
    const float* p0 = base + (top + 4 * i + 1) * Wim + left + 4 * j + 1;
    const float* p1 = p0 + Wim;
#pragma unroll
    for (int q = 0; q < 4; ++q)
      v[q] = .25f * (p0[4 * q] + p0[4 * q + 1] + p1[4 * q] + p1[4 * q + 1]);
  }
  unsigned short h[4], l[4];
#pragma unroll
  for (int q = 0; q < 4; ++q) {
    h[q] = f2bf(v[q]);
    l[q] = f2bf(v[q] - bf2f(h[q]));
  }
  int off = (r >> 3) * 2048 + b * 8 + (r & 7);
  *(ushort4*)(ghi + off) = make_ushort4(h[0], h[1], h[2], h[3]);
  *(ushort4*)(glo + off) = make_ushort4(l[0], l[1], l[2], l[3]);
}

// pack 8 fp32 -> 8 bf16-hi (trunc) + 8 bf16-lo(exact residual, trunc)
__device__ __forceinline__ void pack8(const float v[8], uint4& hi, uint4& lo) {
  unsigned h[4], l[4];
#pragma unroll
  for (int p = 0; p < 4; ++p) {
    unsigned u0 = __float_as_uint(v[2 * p]), u1 = __float_as_uint(v[2 * p + 1]);
    unsigned m0 = u0 & 0xffff0000u, m1 = u1 & 0xffff0000u;
    h[p] = __byte_perm(u0, u1, 0x7632);
    float l0 = v[2 * p] - __uint_as_float(m0);
    float l1 = v[2 * p + 1] - __uint_as_float(m1);
    l[p] = __byte_perm(__float_as_uint(l0), __float_as_uint(l1), 0x7632);
  }
  hi = make_uint4(h[0], h[1], h[2], h[3]);
  lo = make_uint4(l[0], l[1], l[2], l[3]);
}

// ---------------------------------------------------------------------------
// GEMM core: BM=128, BN=128, BK=32, 4 waves as 2x2 of 64x64 tiles,
// v_mfma_f32_32x32x16_bf16, bf16x3 split. A: blocked bf16 hi/lo [kblk][M][8].
// B: fp32 [K][N] read coalesced, hi/lo split in registers (trunc+exact-lo),
// written as contiguous conflict-free ds_write_b128 in fragment layout.
// Depth-2 register prefetch; iters is compile-time -> full unroll.
// ---------------------------------------------------------------------------
__device__ __forceinline__ void gemm_core(
    const unsigned short* __restrict__ Ahi, const unsigned short* __restrict__ Alo,
    int Mtot, int m0,
    const float* __restrict__ Bf, int Ntot, int n0,
    int kb0, int iters, f32x16 acc[2][2], unsigned short* __restrict__ lds) {
  const int t = threadIdx.x, lane = t & 63;
  const int wm = t >> 7, wn = (t >> 6) & 1;
  const int l5 = lane & 31, lh = lane >> 5;
  unsigned short* lAh = lds;
  unsigned short* lAl = lds + 4096;
  unsigned short* lBh = lds + 8192;
  unsigned short* lBl = lds + 12288;

  const int kblk0 = kb0 >> 3;
  long aoff[2];
#pragma unroll
  for (int q = 0; q < 2; ++q) {
    int s = q * 256 + t;
    aoff[q] = ((long)(kblk0 + (s >> 7)) * Mtot + m0 + (s & 127)) * 8;
  }
  const long dA = (long)Mtot * 32;            // 4 kblks per iter
  const int bn = t & 127, bkh = t >> 7;       // B: n owned, k-half (16 k's)
  const float* bptr = Bf + ((long)kb0 + bkh * 16) * Ntot + n0 + bn;
  const int bslot = (bkh * 2) * 128 + bn;     // first of 2 kgroup slots

  uint4 rAh[2][2], rAl[2][2];
  float rB[2][16];
#pragma unroll
  for (int pb = 0; pb < 2; ++pb) {
    if (pb < iters) {
#pragma unroll
      for (int q = 0; q < 2; ++q) {
        rAh[pb][q] = *(const uint4*)(Ahi + aoff[q] + pb * dA);
        rAl[pb][q] = *(const uint4*)(Alo + aoff[q] + pb * dA);
      }
#pragma unroll
      for (int jj = 0; jj < 16; ++jj)
        rB[pb][jj] = bptr[(long)(pb * 32 + jj) * Ntot];
    }
  }

#pragma unroll
  for (int it = 0; it < iters; ++it) {
    const int pb = it & 1;
    __syncthreads();
#pragma unroll
    for (int q = 0; q < 2; ++q) {
      int d = (q * 256 + t) * 8;
      *(uint4*)(lAh + d) = rAh[pb][q];
      *(uint4*)(lAl + d) = rAl[pb][q];
    }
#pragma unroll
    for (int oct = 0; oct < 2; ++oct) {
      uint4 hi, lo;
      pack8(&rB[pb][oct * 8], hi, lo);
      int d = (bslot + oct * 128) * 8;
      *(uint4*)(lBh + d) = hi;
      *(uint4*)(lBl + d) = lo;
    }
    __syncthreads();
    if (it + 2 < iters) {
#pragma unroll
      for (int q = 0; q < 2; ++q) {
        rAh[pb][q] = *(const uint4*)(Ahi + aoff[q] + (long)(it + 2) * dA);
        rAl[pb][q] = *(const uint4*)(Alo + aoff[q] + (long)(it + 2) * dA);
      }
#pragma unroll
      for (int jj = 0; jj < 16; ++jj)
        rB[pb][jj] = bptr[(long)((it + 2) * 32 + jj) * Ntot];
    }
#pragma unroll
    for (int ks = 0; ks < 2; ++ks) {
      short8 fah[2], fal[2], fbh[2], fbl[2];
#pragma unroll
      for (int mi = 0; mi < 2; ++mi) {
        int off = ((ks * 2 + lh) * 128 + wm * 64 + mi * 32 + l5) * 8;
        fah[mi] = *(const short8*)(lAh + off);
        fal[mi] = *(const short8*)(lAl + off);
      }
#pragma unroll
      for (int ni = 0; ni < 2; ++ni) {
        int off = ((ks * 2 + lh) * 128 + wn * 64 + ni * 32 + l5) * 8;
        fbh[ni] = *(const short8*)(lBh + off);
        fbl[ni] = *(const short8*)(lBl + off);
      }
#pragma unroll
      for (int mi = 0; mi < 2; ++mi)
#pragma unroll
        for (int ni = 0; ni < 2; ++ni)
          acc[mi][ni] = __builtin_amdgcn_mfma_f32_32x32x16_bf16(fah[mi], fbh[ni], acc[mi][ni], 0, 0, 0);
#pragma unroll
      for (int mi = 0; mi < 2; ++mi)
#pragma unroll
        for (int ni = 0; ni < 2; ++ni)
          acc[mi][ni] = __builtin_amdgcn_mfma_f32_32x32x16_bf16(fah[mi], fbl[ni], acc[mi][ni], 0, 0, 0);
#pragma unroll
      for (int mi = 0; mi < 2; ++mi)
#pragma unroll
        for (int ni = 0; ni < 2; ++ni)
          acc[mi][ni] = __builtin_amdgcn_mfma_f32_32x32x16_bf16(fal[mi], fbh[ni], acc[mi][ni], 0, 0, 0);
    }
  }
}

// C/D 32x32: col = lane&31, row = (reg&3) + 8*(reg>>2) + 4*(lane>>5)
__device__ __forceinline__ void epilogue(float* __restrict__ Pz, int ldp, int m0,
                                         int n0, f32x16 acc[2][2]) {
  const int t = threadIdx.x, lane = t & 63;
  const int wm = t >> 7, wn = (t >> 6) & 1;
  const int l5 = lane & 31, lh = lane >> 5;
#pragma unroll
  for (int mi = 0; mi < 2; ++mi)
#pragma unroll
    for (int ni = 0; ni < 2; ++ni) {
      int col = n0 + wn * 64 + ni * 32 + l5;
      int rbase = m0 + wm * 64 + mi * 32 + 4 * lh;
#pragma unroll
      for (int r = 0; r < 16; ++r) {
        int row = rbase + (r & 3) + 8 * (r >> 2);
        Pz[(long)row * ldp + col] = acc[mi][ni][r];
      }
    }
}

// gemm1: grid (8 n, 2 m, 32 z); K-chunk 288 (9 iters), W1 fp32 staged in-kernel
__global__ __launch_bounds__(256, 2) void gemm1_kernel(
    const unsigned short* __restrict__ ghi, const unsigned short* __restrict__ glo,
    const float* __restrict__ W1, float* __restrict__ P) {
  __shared__ __align__(16) unsigned short lds[16384];
  f32x16 acc[2][2];
#pragma unroll
  for (int i = 0; i < 2; ++i)
#pragma unroll
    for (int j = 0; j < 2; ++j)
#pragma unroll
      for (int r = 0; r < 16; ++r) acc[i][j][r] = 0.f;
  int n0 = blockIdx.x * 128, m0 = blockIdx.y * 128, z = blockIdx.z;
  gemm_core(ghi, glo, Bsz, m0, W1, HG, n0, z * 288, 9, acc, lds);
  epilogue(P + (long)z * Bsz * HG, HG, m0, n0, acc);
}

// gemm2: grid (10 n, 2 m, 10 z); z<8: h1@W3 chunk 128; z=8,9: h2@W4 chunk 128
__global__ __launch_bounds__(256, 2) void gemm2_kernel(
    const unsigned short* __restrict__ h1h, const unsigned short* __restrict__ h1l,
    const unsigned short* __restrict__ h2h, const unsigned short* __restrict__ h2l,
    const float* __restrict__ W3, const float* __restrict__ W4,
    float* __restrict__ P) {
  __shared__ __align__(16) unsigned short lds[16384];
  f32x16 acc[2][2];
#pragma unroll
  for (int i = 0; i < 2; ++i)
#pragma unroll
    for (int j = 0; j < 2; ++j)
#pragma unroll
      for (int r = 0; r < 16; ++r) acc[i][j][r] = 0.f;
  int n0 = blockIdx.x * 128, m0 = blockIdx.y * 128, z = blockIdx.z;
  if (z < 8)
    gemm_core(h1h, h1l, Bsz, m0, W3, NOUT, n0, z * 128, 4, acc, lds);
  else
    gemm_core(h2h, h2l, Bsz, m0, W4, NOUT, n0, (z - 8) * 128, 4, acc, lds);
  epilogue(P + (long)z * Bsz * NOUT, NOUT, m0, n0, acc);
}

// reduce1 (bx<256): h1 = relu(b1 + sum_{z<32} P1[z]) -> blocked hi/lo
// h2 (bx>=256): h2 = relu(loc @ W2 + b2)             -> blocked hi/lo
__global__ __launch_bounds__(256) void reduce1_h2_kernel(
    const float* __restrict__ P, const float* __restrict__ b1,
    const float* __restrict__ loc, const float* __restrict__ W2,
    const float* __restrict__ b2,
    unsigned short* __restrict__ h1h, unsigned short* __restrict__ h1l,
    unsigned short* __restrict__ h2h, unsigned short* __restrict__ h2l) {
  if (blockIdx.x < 256) {
    int i4 = (blockIdx.x * 256 + threadIdx.x) * 4;
    float4 s = *(const float4*)(P + i4);
    for (int z = 1; z < 32; ++z) {
      float4 p = *(const float4*)(P + (long)z * (Bsz * HG) + i4);
      s.x += p.x; s.y += p.y; s.z += p.z; s.w += p.w;
    }
    int m = i4 >> 10, k = i4 & (HG - 1);
    float4 bb = *(const float4*)(b1 + k);
    float v0 = fmaxf(s.x + bb.x, 0.f), v1 = fmaxf(s.y + bb.y, 0.f);
    float v2 = fmaxf(s.z + bb.z, 0.f), v3 = fmaxf(s.w + bb.w, 0.f);
    unsigned short h0 = f2bf(v0), h1 = f2bf(v1), h2 = f2bf(v2), h3 = f2bf(v3);
    int off = (k >> 3) * 2048 + m * 8 + (k & 7);
    *(ushort4*)(h1h + off) = make_ushort4(h0, h1, h2, h3);
    *(ushort4*)(h1l + off) = make_ushort4(f2bf(v0 - bf2f(h0)), f2bf(v1 - bf2f(h1)),
                                          f2bf(v2 - bf2f(h2)), f2bf(v3 - bf2f(h3)));
  } else {
    int i4 = ((blockIdx.x - 256) * 256 + threadIdx.x) * 4;
    int b = i4 >> 8, k = i4 & (HL - 1);
    float l0 = loc[b * 2 + 0], l1 = loc[b * 2 + 1];
    float4 w0 = *(const float4*)(W2 + k);
    float4 w1 = *(const float4*)(W2 + HL + k);
    float4 bb = *(const float4*)(b2 + k);
    float v0 = fmaxf(fmaf(l0, w0.x, fmaf(l1, w1.x, bb.x)), 0.f);
    float v1 = fmaxf(fmaf(l0, w0.y, fmaf(l1, w1.y, bb.y)), 0.f);
    float v2 = fmaxf(fmaf(l0, w0.z, fmaf(l1, w1.z, bb.z)), 0.f);
    float v3 = fmaxf(fmaf(l0, w0.w, fmaf(l1, w1.w, bb.w)), 0.f);
    unsigned short h0 = f2bf(v0), h1 = f2bf(v1), h2 = f2bf(v2), h3 = f2bf(v3);
    int off = (k >> 3) * 2048 + b * 8 + (k & 7);
    *(ushort4*)(h2h + off) = make_ushort4(h0, h1, h2, h3);
    *(ushort4*)(h2l + off) = make_ushort4(f2bf(v0 - bf2f(h0)), f2bf(v1 - bf2f(h1)),
                                          f2bf(v2 - bf2f(h2)), f2bf(v3 - bf2f(h3)));
  }
}

// reduce2: out = relu(relu(b3 + sum_{z<8} P2[z]) + relu(b4 + P2[8] + P2[9]))
__global__ __launch_bounds__(256) void reduce2_kernel(
    const float* __restrict__ P, const float* __restrict__ b3,
    const float* __restrict__ b4, float* __restrict__ out) {
  int i4 = (blockIdx.x * 256 + threadIdx.x) * 4;
  const long S = (long)Bsz * NOUT;
  float4 a = *(const float4*)(P + i4);
  for (int z = 1; z < 8; ++z) {
    float4 p = *(const float4*)(P + z * S + i4);
    a.x += p.x; a.y += p.y; a.z += p.z; a.w += p.w;
  }
  float4 c8 = *(const float4*)(P + 8 * S + i4);
  float4 c9 = *(const float4*)(P + 9 * S + i4);
  int n = i4 % NOUT;
  float4 b3v = *(const float4*)(b3 + n);
  float4 b4v = *(const float4*)(b4 + n);
  float4 o;
  o.x = fmaxf(fmaxf(a.x + b3v.x, 0.f) + fmaxf(c8.x + c9.x + b4v.x, 0.f), 0.f);
  o.y = fmaxf(fmaxf(a.y + b3v.y, 0.f) + fmaxf(c8.y + c9.y + b4v.y, 0.f), 0.f);
  o.z = fmaxf(fmaxf(a.z + b3v.z, 0.f) + fmaxf(c8.z + c9.z + b4v.z, 0.f), 0.f);
  o.w = fmaxf(fmaxf(a.w + b3v.w, 0.f) + fmaxf(c8.w + c9.w + b4v.w, 0.f), 0.f);
  *(float4*)(out + i4) = o;
}

extern "C" void kernel_launch(void* const* d_in, const int* in_sizes, int n_in,
                              void* d_out, int out_size, void* d_ws, size_t ws_size,
                              hipStream_t stream) {
  const float* images = (const float*)d_in[0];
  const float* locs = (const float*)d_in[1];
  const float* W1 = (const float*)d_in[2];
  const float* b1 = (const float*)d_in[3];
  const float* W2 = (const float*)d_in[4];
  const float* b2 = (const float*)d_in[5];
  const float* W3 = (const float*)d_in[6];
  const float* b3 = (const float*)d_in[7];
  const float* W4 = (const float*)d_in[8];
  const float* b4 = (const float*)d_in[9];
  float* out = (float*)d_out;

  unsigned short* p = (unsigned short*)d_ws;
  unsigned short* gsh = p; p += 2359296;
  unsigned short* gsl = p; p += 2359296;
  unsigned short* h1h = p; p += 262144;
  unsigned short* h1l = p; p += 262144;
  unsigned short* h2h = p; p += 65536;
  unsigned short* h2l = p; p += 65536;
  float* P1 = (float*)p;            // 32*256*1024 = 8,388,608 floats
  float* P2 = P1 + 8388608;         // 10*256*1280 = 3,276,800 floats

  foveate_kernel<<<2304, 256, 0, stream>>>(images, locs, gsh, gsl);
  gemm1_kernel<<<dim3(8, 2, 32), 256, 0, stream>>>(gsh, gsl, W1, P1);
  reduce1_h2_kernel<<<320, 256, 0, stream>>>(P1, b1, locs, W2, b2, h1h, h1l, h2h, h2l);
  gemm2_kernel<<<dim3(10, 2, 10), 256, 0, stream>>>(h1h, h1l, h2h, h2l, W3, W4, P2);
  reduce2_kernel<<<320, 256, 0, stream>>>(P2, b3, b4, out);
}